// Round 1
// baseline (1315.538 us; speedup 1.0000x reference)
//
#include <hip/hip_runtime.h>
#include <hip/hip_fp16.h>
#include <math.h>

#define B_SZ 64
#define T_SZ 512
#define M_TOT (B_SZ * T_SZ)   // 32768 tokens
#define HSTR  160             // uints per weight row (320 halves; cols >=300 zero)
#define NPASS 11              // fixed-point refinement passes (halo 16 >= NPASS)
#define BROW  328             // halves per LDS G-buffer row (164 uints ≡ 4 mod 32)

typedef _Float16 f16x8 __attribute__((ext_vector_type(8)));
typedef float    f32x4 __attribute__((ext_vector_type(4)));

__device__ __forceinline__ unsigned int packrte(float a, float b) {
    __half2 h = __floats2half2_rn(a, b);
    return __builtin_bit_cast(unsigned int, h);
}
__device__ __forceinline__ float sigm(float v) {
    return 1.f / (1.f + __expf(-v));
}

// =====================================================================
// Weights fp32 -> packed f16x2, zero-padded to 320 rows x 320 cols.
// grid (320, 4): m=0 fc1_w, m=1 l1_w x-part, m=2 l2_w, m=3 l1_w h-part.
// Padded rows remove all N-predicates from the fused kernel's hot loop.
// =====================================================================
__global__ __launch_bounds__(160) void wconv(
    const float* __restrict__ fc1_w, const float* __restrict__ l1_w,
    const float* __restrict__ l2_w, unsigned int* __restrict__ Wh)
{
    const int r = blockIdx.x, m = blockIdx.y, j = threadIdx.x;
    const float* src; int stride, off;
    if (m == 0)      { src = fc1_w; stride = 300; off = 0; }
    else if (m == 1) { src = l1_w;  stride = 600; off = 0; }
    else if (m == 2) { src = l2_w;  stride = 300; off = 0; }
    else             { src = l1_w;  stride = 600; off = 300; }
    int k = 2 * j;
    bool rv = (r < 300);
    float a = (rv && k     < 300) ? src[(long)r * stride + off + k]     : 0.f;
    float b = (rv && k + 1 < 300) ? src[(long)r * stride + off + k + 1] : 0.f;
    Wh[((long)m * 320 + r) * HSTR + j] = packrte(a, b);
}

// =====================================================================
// Fused kernel: per 64-row output tile (+16-row halo), entirely in LDS:
//   stage emb[x] (f16) -> h = relu(@fc1.T+b) -> xp = h@l1x.T+b (regs, f16)
//   -> G = sigmoid(xp) -> 11x [G = sigmoid(xp + shift(G)@Whh.T)]
//   -> out = G@l2.T, column-max over the 64 output rows -> part.
// Halo 16 >= NPASS makes tiles independent: info moves 1 row per pass.
// 10 waves = 5 m-tiles x 2 n-groups; B streamed from L2 into regs,
// double-buffered one K-chunk (10 uint4) ahead.
// =====================================================================
__global__ __launch_bounds__(640) void rnn_mega(
    const int* __restrict__ x, const float* __restrict__ emb,
    const float* __restrict__ fc1_b, const float* __restrict__ l1_b,
    const float* __restrict__ l2_b, const unsigned int* __restrict__ Wh,
    float* __restrict__ part)
{
    __shared__ _Float16 Gt[81 * BROW];   // row 0 = zero shift-source
    __shared__ float red[4 * 320];

    const int tid  = threadIdx.x;
    const int ww   = tid >> 6;
    const int lane = tid & 63;
    const int ml   = lane & 15;
    const int q    = lane >> 4;
    const int mt   = ww % 5;      // m-tile (16 rows each, M=80)
    const int ng   = ww / 5;      // n-group (160 cols each, N=320)
    const int m0   = blockIdx.x * 64;
    const int m0h  = m0 - 16;
    const bool bstart = (m0 & (T_SZ - 1)) == 0;   // tile starts a batch row

    const unsigned int* W1  = Wh;
    const unsigned int* W2x = Wh + 320 * HSTR;
    const unsigned int* W3  = Wh + 2 * 320 * HSTR;
    const unsigned int* Whh = Wh + 3 * 320 * HSTR;

    // ---- stage emb[x[m0h..m0h+80)] as f16 into Gt rows 1..80 (pads zero)
    #pragma unroll
    for (int it = 0; it < 5; ++it) {
        int li  = it * 640 + tid;      // 0..3199
        int row = li / 40;             // 0..79
        int sg  = li % 40;             // 8-half segment
        int g   = m0h + row; if (g < 0) g = 0;   // block 0 halo clamp
        const float* er = emb + (long)x[g] * 300;
        int k = sg * 8;
        float4 f0 = (k + 4 <= 300) ? *(const float4*)(er + k)     : make_float4(0,0,0,0);
        float4 f1 = (k + 8 <= 300) ? *(const float4*)(er + k + 4) : make_float4(0,0,0,0);
        uint4 u = make_uint4(packrte(f0.x, f0.y), packrte(f0.z, f0.w),
                             packrte(f1.x, f1.y), packrte(f1.z, f1.w));
        *(uint4*)&Gt[(row + 1) * BROW + sg * 8] = u;
    }
    if (tid < 41) *(uint4*)&Gt[tid * 8] = make_uint4(0, 0, 0, 0);  // row 0 = 0
    __syncthreads();

    f32x4 acc[10];

    // GEMM over the LDS tile: acc[nt] += A(rows mt*16+.. +ro) @ Bb.T
    // ro=1: unshifted (reads buffer rows 1..80); ro=0: shifted (rows 0..79).
    auto run_gemm = [&](const unsigned int* __restrict__ Bb, int ro) {
        #pragma unroll
        for (int nt = 0; nt < 10; ++nt) acc[nt] = (f32x4){0.f, 0.f, 0.f, 0.f};
        const _Float16* ap = &Gt[(mt * 16 + ml + ro) * BROW + q * 8];
        const unsigned int* bp = Bb + (long)(ng * 160 + ml) * HSTR + q * 4;
        f16x8 a_cur = *(const f16x8*)ap;
        uint4 b_cur[10];
        #pragma unroll
        for (int nt = 0; nt < 10; ++nt)
            b_cur[nt] = *(const uint4*)(bp + nt * 16 * HSTR);
        #pragma unroll
        for (int kc = 0; kc < 10; ++kc) {
            f16x8 a_nxt; uint4 b_nxt[10];
            if (kc < 9) {
                a_nxt = *(const f16x8*)(ap + (kc + 1) * 32);
                #pragma unroll
                for (int nt = 0; nt < 10; ++nt)
                    b_nxt[nt] = *(const uint4*)(bp + nt * 16 * HSTR + (kc + 1) * 16);
            }
            #pragma unroll
            for (int nt = 0; nt < 10; ++nt)
                acc[nt] = __builtin_amdgcn_mfma_f32_16x16x32_f16(
                    a_cur, __builtin_bit_cast(f16x8, b_cur[nt]), acc[nt], 0, 0, 0);
            a_cur = a_nxt;
            #pragma unroll
            for (int nt = 0; nt < 10; ++nt) b_cur[nt] = b_nxt[nt];
        }
    };

    // ---- h = relu(embf16 @ fc1.T + fc1_b) -> overwrite Gt rows 1..80
    run_gemm(W1, 1);
    __syncthreads();                  // all reads of staged emb done
    #pragma unroll
    for (int nt = 0; nt < 10; ++nt) {
        int col = ng * 160 + nt * 16 + ml;
        float bb = fc1_b[col < 300 ? col : 0];
        #pragma unroll
        for (int r = 0; r < 4; ++r) {
            int trow = mt * 16 + q * 4 + r;
            float v = fmaxf(acc[nt][r] + bb, 0.f);
            Gt[(trow + 1) * BROW + col] = (col < 300) ? (_Float16)v : (_Float16)0.f;
        }
    }
    __syncthreads();

    // ---- xp = h @ l1_wx.T + l1_b  (held as packed f16 in regs, exact
    //      same rounding as the old global Xp f16 store)
    run_gemm(W2x, 1);
    unsigned int xpk[10][2];
    #pragma unroll
    for (int nt = 0; nt < 10; ++nt) {
        int col = ng * 160 + nt * 16 + ml;
        float bb = (col < 300) ? l1_b[col < 300 ? col : 0] : 0.f;
        xpk[nt][0] = packrte(acc[nt][0] + bb, acc[nt][1] + bb);
        xpk[nt][1] = packrte(acc[nt][2] + bb, acc[nt][3] + bb);
    }
    __syncthreads();                  // all reads of h done
    // ---- G init = sigmoid(xp); force pads and (bstart) row t=m0-1 to 0
    #pragma unroll
    for (int nt = 0; nt < 10; ++nt) {
        int col = ng * 160 + nt * 16 + ml;
        #pragma unroll
        for (int r = 0; r < 4; ++r) {
            int trow = mt * 16 + q * 4 + r;
            __half2 h2 = __builtin_bit_cast(__half2, xpk[nt][r >> 1]);
            float xv = (r & 1) ? __high2float(h2) : __low2float(h2);
            float v = sigm(xv);
            bool zz = (col >= 300) || (bstart && trow == 15);
            Gt[(trow + 1) * BROW + col] = zz ? (_Float16)0.f : (_Float16)v;
        }
    }
    __syncthreads();

    // ---- 11 fixed-point passes, all in LDS
    #pragma unroll 1
    for (int p = 0; p < NPASS; ++p) {
        run_gemm(Whh, 0);             // shifted read: row t uses G[t-1]
        __syncthreads();              // all A-reads done before overwrite
        #pragma unroll
        for (int nt = 0; nt < 10; ++nt) {
            int col = ng * 160 + nt * 16 + ml;
            #pragma unroll
            for (int r = 0; r < 4; ++r) {
                int trow = mt * 16 + q * 4 + r;
                __half2 h2 = __builtin_bit_cast(__half2, xpk[nt][r >> 1]);
                float xv = (r & 1) ? __high2float(h2) : __low2float(h2);
                float v = sigm(acc[nt][r] + xv);
                bool zz = (col >= 300) || (bstart && trow == 15);
                Gt[(trow + 1) * BROW + col] = zz ? (_Float16)0.f : (_Float16)v;
            }
        }
        __syncthreads();
    }

    // ---- out = G @ l2.T ; column max over output rows m0..m0+63 only
    if (mt >= 1) {                    // mt 1..4 = tile rows 16..79 (outputs)
        run_gemm(W3, 1);
        #pragma unroll
        for (int nt = 0; nt < 10; ++nt) {
            float v = fmaxf(fmaxf(acc[nt][0], acc[nt][1]),
                            fmaxf(acc[nt][2], acc[nt][3]));
            v = fmaxf(v, __shfl_xor(v, 16));
            v = fmaxf(v, __shfl_xor(v, 32));
            if (lane < 16)
                red[(mt - 1) * 320 + ng * 160 + nt * 16 + lane] = v;
        }
    }
    __syncthreads();
    if (tid < 300) {
        float m = fmaxf(fmaxf(red[tid], red[320 + tid]),
                        fmaxf(red[640 + tid], red[960 + tid]));
        part[(long)blockIdx.x * 320 + tid] = m + l2_b[tid];
    }
}

// =====================================================================
// Final: pooled[b,n] = max over 8 m-chunks of part; out = pooled @ fc2_w.T
// =====================================================================
__global__ __launch_bounds__(320) void fc2_final(
    const float* __restrict__ part,     // [512, 320]
    const float* __restrict__ fc2_w,
    const float* __restrict__ fc2_b,
    float* __restrict__ out)
{
    const int b   = blockIdx.x;
    const int tid = threadIdx.x;
    __shared__ float pooled[304];

    if (tid < 300) {
        float m = part[(long)(b * 8) * 320 + tid];
        #pragma unroll
        for (int c = 1; c < 8; c++)
            m = fmaxf(m, part[(long)(b * 8 + c) * 320 + tid]);
        pooled[tid] = m;
    }
    __syncthreads();

    const int o    = tid >> 6;
    const int lane = tid & 63;
    if (o < 2) {
        float sacc = 0.f;
        for (int jj = lane; jj < 300; jj += 64)
            sacc += pooled[jj] * fc2_w[o * 300 + jj];
        #pragma unroll
        for (int off = 32; off > 0; off >>= 1)
            sacc += __shfl_down(sacc, off);
        if (lane == 0) out[b * 2 + o] = sacc + fc2_b[o];
    }
}

// =====================================================================
extern "C" void kernel_launch(void* const* d_in, const int* in_sizes, int n_in,
                              void* d_out, int out_size, void* d_ws, size_t ws_size,
                              hipStream_t stream)
{
    const int*   x     = (const int*)  d_in[0];
    const float* emb   = (const float*)d_in[1];
    const float* fc1_w = (const float*)d_in[2];
    const float* fc1_b = (const float*)d_in[3];
    const float* l1_w  = (const float*)d_in[4];
    const float* l1_b  = (const float*)d_in[5];
    const float* l2_w  = (const float*)d_in[6];
    const float* l2_b  = (const float*)d_in[7];
    const float* fc2_w = (const float*)d_in[8];
    const float* fc2_b = (const float*)d_in[9];
    float* out = (float*)d_out;

    // ws: part [512*320 f32] | Wh [4*320*160 uints]  (~1.5 MB total)
    float* part = (float*)d_ws;
    unsigned int* Wh = (unsigned int*)(part + (size_t)512 * 320);

    wconv<<<dim3(320, 4), 160, 0, stream>>>(fc1_w, l1_w, l2_w, Wh);
    rnn_mega<<<M_TOT / 64, 640, 0, stream>>>(x, emb, fc1_b, l1_b, l2_b, Wh, part);
    fc2_final<<<B_SZ, 320, 0, stream>>>(part, fc2_w, fc2_b, out);
}

// Round 2
// 455.219 us; speedup vs baseline: 2.8899x; 2.8899x over previous
//
#include <hip/hip_runtime.h>
#include <hip/hip_fp16.h>
#include <math.h>

#define B_SZ 64
#define T_SZ 512
#define M_TOT (B_SZ * T_SZ)   // 32768 tokens
#define HSTR  160             // uints per weight row (320 halves; rows/cols >=300 zero)
#define NPASS 11              // fixed-point refinement passes (halo 16 >= NPASS)
#define BROW  328             // halves per LDS G-buffer row (164 uints ≡ 4 mod 32)

typedef _Float16 f16x8 __attribute__((ext_vector_type(8)));
typedef float    f32x4 __attribute__((ext_vector_type(4)));

__device__ __forceinline__ unsigned int packrte(float a, float b) {
    __half2 h = __floats2half2_rn(a, b);
    return __builtin_bit_cast(unsigned int, h);
}
__device__ __forceinline__ float sigm(float v) {
    return 1.f / (1.f + __expf(-v));
}

// =====================================================================
// Weights fp32 -> packed f16x2, zero-padded to 320 rows x 320 cols.
// grid (320, 4): m=0 fc1_w, m=1 l1_w x-part, m=2 l2_w, m=3 l1_w h-part.
// =====================================================================
__global__ __launch_bounds__(160) void wconv(
    const float* __restrict__ fc1_w, const float* __restrict__ l1_w,
    const float* __restrict__ l2_w, unsigned int* __restrict__ Wh)
{
    const int r = blockIdx.x, m = blockIdx.y, j = threadIdx.x;
    const float* src; int stride, off;
    if (m == 0)      { src = fc1_w; stride = 300; off = 0; }
    else if (m == 1) { src = l1_w;  stride = 600; off = 0; }
    else if (m == 2) { src = l2_w;  stride = 300; off = 0; }
    else             { src = l1_w;  stride = 600; off = 300; }
    int k = 2 * j;
    bool rv = (r < 300);
    float a = (rv && k     < 300) ? src[(long)r * stride + off + k]     : 0.f;
    float b = (rv && k + 1 < 300) ? src[(long)r * stride + off + k + 1] : 0.f;
    Wh[((long)m * 320 + r) * HSTR + j] = packrte(a, b);
}

// =====================================================================
// Fused per-64-row-tile kernel (16-row halo >= NPASS makes tiles exact):
//   stage emb[x] f16 -> h = relu(@fc1.T+b) -> xp = h@l1x.T+b (f16, regs)
//   -> G = sigm(xp) -> 11x [G = sigm(xp + shift(G)@Whh.T)] -> G@l2.T max.
// 10 waves; wave owns 32 output cols (2 n-tiles) and loops all 5 m-tiles.
// B fragments live in registers (bf[2][5], one K-half at a time, from
// L2-resident 800KB weights); A fragments ds_read from the LDS G tile.
// Live regs ~140 (acc 40 + bf 40 + xpk 20) -> fits 3 waves/SIMD @ <=170.
// =====================================================================
__global__ __launch_bounds__(640, 3) void rnn_mega(
    const int* __restrict__ x, const float* __restrict__ emb,
    const float* __restrict__ fc1_b, const float* __restrict__ l1_b,
    const float* __restrict__ l2_b, const unsigned int* __restrict__ Wh,
    float* __restrict__ part)
{
    __shared__ _Float16 Gt[81 * BROW];   // row 0 = zero shift-source

    const int tid  = threadIdx.x;
    const int ww   = tid >> 6;
    const int lane = tid & 63;
    const int ml   = lane & 15;
    const int q    = lane >> 4;
    const int c0   = ww * 32;            // this wave's output columns
    const int m0   = blockIdx.x * 64;
    const int m0h  = m0 - 16;
    const bool bstart = (m0 & (T_SZ - 1)) == 0;

    const unsigned int* W1  = Wh;
    const unsigned int* W2x = Wh + 320 * HSTR;
    const unsigned int* W3  = Wh + 2 * 320 * HSTR;
    const unsigned int* Whh = Wh + 3 * 320 * HSTR;

    // ---- stage emb[x[m0h..m0h+80)] as f16 into Gt rows 1..80
    #pragma unroll
    for (int it = 0; it < 5; ++it) {
        int li  = it * 640 + tid;      // 0..3199
        int row = li / 40;             // 0..79
        int sg  = li % 40;             // 8-half segment
        int g   = m0h + row; if (g < 0) g = 0;   // block 0 halo clamp
        const float* er = emb + (long)x[g] * 300;
        int k = sg * 8;
        float4 f0 = (k + 4 <= 300) ? *(const float4*)(er + k)     : make_float4(0,0,0,0);
        float4 f1 = (k + 8 <= 300) ? *(const float4*)(er + k + 4) : make_float4(0,0,0,0);
        uint4 u = make_uint4(packrte(f0.x, f0.y), packrte(f0.z, f0.w),
                             packrte(f1.x, f1.y), packrte(f1.z, f1.w));
        *(uint4*)&Gt[(row + 1) * BROW + sg * 8] = u;
    }
    if (tid < 41) *(uint4*)&Gt[tid * 8] = make_uint4(0, 0, 0, 0);  // row 0 = 0
    __syncthreads();

    f32x4        acc[5][2];
    uint4        bf[2][5];
    unsigned int xpk[5][2][2];

    // B-fragment load: rows c0+nt*16+ml of matrix Bb, K-chunks kb..kb+4
    #define LOADB(Bb, kb) { \
        _Pragma("unroll") for (int nt = 0; nt < 2; ++nt) \
        _Pragma("unroll") for (int kk = 0; kk < 5; ++kk) \
            bf[nt][kk] = *(const uint4*)((Bb) + (c0 + nt * 16 + ml) * HSTR \
                                              + ((kb) + kk) * 16 + q * 4); }
    // one K-half of the GEMM over LDS tile rows (ro=1 unshifted, 0 shifted)
    #define GHALF(ro, kb, MT0) { \
        _Pragma("unroll") for (int mt = (MT0); mt < 5; ++mt) \
        _Pragma("unroll") for (int kk = 0; kk < 5; ++kk) { \
            f16x8 af = *(const f16x8*)&Gt[(mt * 16 + ml + (ro)) * BROW \
                                          + ((kb) + kk) * 32 + q * 8]; \
            acc[mt][0] = __builtin_amdgcn_mfma_f32_16x16x32_f16( \
                af, __builtin_bit_cast(f16x8, bf[0][kk]), acc[mt][0], 0, 0, 0); \
            acc[mt][1] = __builtin_amdgcn_mfma_f32_16x16x32_f16( \
                af, __builtin_bit_cast(f16x8, bf[1][kk]), acc[mt][1], 0, 0, 0); } }
    #define RUN_GEMM(Bb, ro, MT0) { \
        _Pragma("unroll") for (int mt = (MT0); mt < 5; ++mt) { \
            acc[mt][0] = (f32x4){0.f,0.f,0.f,0.f}; \
            acc[mt][1] = (f32x4){0.f,0.f,0.f,0.f}; } \
        LOADB(Bb, 0); GHALF(ro, 0, MT0); \
        LOADB(Bb, 5); GHALF(ro, 5, MT0); }

    // ---- h = relu(embf16 @ fc1.T + fc1_b) -> Gt rows 1..80 (in place)
    RUN_GEMM(W1, 1, 0);
    __syncthreads();                  // all waves done reading staged emb
    #pragma unroll
    for (int mt = 0; mt < 5; ++mt)
    #pragma unroll
    for (int nt = 0; nt < 2; ++nt) {
        int col = c0 + nt * 16 + ml;
        float bb = fc1_b[col < 300 ? col : 0];
        #pragma unroll
        for (int r = 0; r < 4; ++r) {
            int trow = mt * 16 + q * 4 + r;
            float v = fmaxf(acc[mt][nt][r] + bb, 0.f);
            Gt[(trow + 1) * BROW + col] = (col < 300) ? (_Float16)v : (_Float16)0.f;
        }
    }
    __syncthreads();

    // ---- xp = h @ l1_wx.T + l1_b, kept packed f16 in regs (rounding
    //      matches the validated global-Xp-f16 scheme)
    RUN_GEMM(W2x, 1, 0);
    #pragma unroll
    for (int mt = 0; mt < 5; ++mt)
    #pragma unroll
    for (int nt = 0; nt < 2; ++nt) {
        int col = c0 + nt * 16 + ml;
        float bb = (col < 300) ? l1_b[col] : 0.f;
        xpk[mt][nt][0] = packrte(acc[mt][nt][0] + bb, acc[mt][nt][1] + bb);
        xpk[mt][nt][1] = packrte(acc[mt][nt][2] + bb, acc[mt][nt][3] + bb);
    }
    __syncthreads();                  // all waves done reading h
    // ---- G init = sigm(xp); pads and (bstart) row t=m0-1 forced to 0
    #pragma unroll
    for (int mt = 0; mt < 5; ++mt)
    #pragma unroll
    for (int nt = 0; nt < 2; ++nt) {
        int col = c0 + nt * 16 + ml;
        #pragma unroll
        for (int r = 0; r < 4; ++r) {
            int trow = mt * 16 + q * 4 + r;
            __half2 h2 = __builtin_bit_cast(__half2, xpk[mt][nt][r >> 1]);
            float xv = (r & 1) ? __high2float(h2) : __low2float(h2);
            float v = sigm(xv);
            bool zz = (col >= 300) || (bstart && trow == 15);
            Gt[(trow + 1) * BROW + col] = zz ? (_Float16)0.f : (_Float16)v;
        }
    }
    __syncthreads();

    // ---- 11 fixed-point passes, all in LDS
    #pragma unroll 1
    for (int p = 0; p < NPASS; ++p) {
        const int mt0 = (p == NPASS - 1) ? 1 : 0;   // last pass: halo dead
        if (mt0) { RUN_GEMM(Whh, 0, 1); } else { RUN_GEMM(Whh, 0, 0); }
        __syncthreads();              // all A-reads done before overwrite
        #pragma unroll
        for (int mt = 0; mt < 5; ++mt) {
            if (mt < mt0) continue;
            #pragma unroll
            for (int nt = 0; nt < 2; ++nt) {
                int col = c0 + nt * 16 + ml;
                #pragma unroll
                for (int r = 0; r < 4; ++r) {
                    int trow = mt * 16 + q * 4 + r;
                    __half2 h2 = __builtin_bit_cast(__half2, xpk[mt][nt][r >> 1]);
                    float xv = (r & 1) ? __high2float(h2) : __low2float(h2);
                    float v = sigm(acc[mt][nt][r] + xv);
                    bool zz = (col >= 300) || (bstart && trow == 15);
                    Gt[(trow + 1) * BROW + col] = zz ? (_Float16)0.f : (_Float16)v;
                }
            }
        }
        __syncthreads();
    }

    // ---- out = G @ l2.T over output rows only (mt 1..4 = rows m0..m0+63);
    //      each wave owns its 32 cols exclusively -> pure-shfl column max
    RUN_GEMM(W3, 1, 1);
    #pragma unroll
    for (int nt = 0; nt < 2; ++nt) {
        float v = acc[1][nt][0];
        #pragma unroll
        for (int mt = 1; mt < 5; ++mt)
        #pragma unroll
        for (int r = 0; r < 4; ++r)
            v = fmaxf(v, acc[mt][nt][r]);
        v = fmaxf(v, __shfl_xor(v, 16));
        v = fmaxf(v, __shfl_xor(v, 32));
        if (lane < 16) {
            int col = c0 + nt * 16 + lane;
            part[(long)blockIdx.x * 320 + col] =
                v + ((col < 300) ? l2_b[col] : 0.f);
        }
    }
    #undef LOADB
    #undef GHALF
    #undef RUN_GEMM
}

// =====================================================================
// Final: pooled[b,n] = max over 8 m-chunks of part; out = pooled @ fc2_w.T
// =====================================================================
__global__ __launch_bounds__(320) void fc2_final(
    const float* __restrict__ part,     // [512, 320]
    const float* __restrict__ fc2_w,
    const float* __restrict__ fc2_b,
    float* __restrict__ out)
{
    const int b   = blockIdx.x;
    const int tid = threadIdx.x;
    __shared__ float pooled[304];

    if (tid < 300) {
        float m = part[(long)(b * 8) * 320 + tid];
        #pragma unroll
        for (int c = 1; c < 8; c++)
            m = fmaxf(m, part[(long)(b * 8 + c) * 320 + tid]);
        pooled[tid] = m;
    }
    __syncthreads();

    const int o    = tid >> 6;
    const int lane = tid & 63;
    if (o < 2) {
        float sacc = 0.f;
        for (int jj = lane; jj < 300; jj += 64)
            sacc += pooled[jj] * fc2_w[o * 300 + jj];
        #pragma unroll
        for (int off = 32; off > 0; off >>= 1)
            sacc += __shfl_down(sacc, off);
        if (lane == 0) out[b * 2 + o] = sacc + fc2_b[o];
    }
}

// =====================================================================
extern "C" void kernel_launch(void* const* d_in, const int* in_sizes, int n_in,
                              void* d_out, int out_size, void* d_ws, size_t ws_size,
                              hipStream_t stream)
{
    const int*   x     = (const int*)  d_in[0];
    const float* emb   = (const float*)d_in[1];
    const float* fc1_w = (const float*)d_in[2];
    const float* fc1_b = (const float*)d_in[3];
    const float* l1_w  = (const float*)d_in[4];
    const float* l1_b  = (const float*)d_in[5];
    const float* l2_w  = (const float*)d_in[6];
    const float* l2_b  = (const float*)d_in[7];
    const float* fc2_w = (const float*)d_in[8];
    const float* fc2_b = (const float*)d_in[9];
    float* out = (float*)d_out;

    // ws: part [512*320 f32] | Wh [4*320*160 uints]  (~1.5 MB total)
    float* part = (float*)d_ws;
    unsigned int* Wh = (unsigned int*)(part + (size_t)512 * 320);

    wconv<<<dim3(320, 4), 160, 0, stream>>>(fc1_w, l1_w, l2_w, Wh);
    rnn_mega<<<M_TOT / 64, 640, 0, stream>>>(x, emb, fc1_b, l1_b, l2_b, Wh, part);
    fc2_final<<<B_SZ, 320, 0, stream>>>(part, fc2_w, fc2_b, out);
}